// Round 11
// baseline (1020.213 us; speedup 1.0000x reference)
//
#include <hip/hip_runtime.h>
#include <hip/hip_bf16.h>

#define NN 4096

typedef unsigned short u16;
using bf16x8 = __attribute__((ext_vector_type(8))) short;
using f32x16 = __attribute__((ext_vector_type(16))) float;
using u32x4  = __attribute__((ext_vector_type(4))) unsigned int;

// round-to-nearest-even f32 -> bf16 bits
__device__ inline u16 f2bf(float f) {
    union { float f; unsigned u; } c; c.f = f;
    unsigned r = (c.u + 0x7fffu + ((c.u >> 16) & 1u)) >> 16;
    return (u16)r;
}

__device__ inline void gld16(const void* g, void* l) {
    __builtin_amdgcn_global_load_lds(
        (const __attribute__((address_space(1))) void*)g,
        (__attribute__((address_space(3))) void*)l, 16, 0, 0);
}

__device__ inline bf16x8 negbf(bf16x8 v) {
    u32x4 u; __builtin_memcpy(&u, &v, 16);
    u ^= 0x80008000u;
    bf16x8 r; __builtin_memcpy(&r, &u, 16);
    return r;
}

// ---------------- f32 -> bf16 convert ----------------
__global__ __launch_bounds__(256) void cvt_bf16(const float* __restrict__ s,
                                                u16* __restrict__ d) {
    size_t i = ((size_t)blockIdx.x * 256 + threadIdx.x) * 8;
    float4 v0 = *(const float4*)(s + i);
    float4 v1 = *(const float4*)(s + i + 4);
    bf16x8 o;
    o[0] = (short)f2bf(v0.x); o[1] = (short)f2bf(v0.y);
    o[2] = (short)f2bf(v0.z); o[3] = (short)f2bf(v0.w);
    o[4] = (short)f2bf(v1.x); o[5] = (short)f2bf(v1.y);
    o[6] = (short)f2bf(v1.z); o[7] = (short)f2bf(v1.w);
    *(bf16x8*)(d + i) = o;
}

// ---------------- transpose + convert: d[m][k] = bf16(s[k][m]) ----------------
__global__ __launch_bounds__(256) void tr_cvt(const float* __restrict__ s,
                                              u16* __restrict__ d) {
    __shared__ float t[32][33];
    int x  = blockIdx.x * 32 + threadIdx.x;
    int y0 = blockIdx.y * 32;
#pragma unroll
    for (int j = 0; j < 32; j += 8)
        t[threadIdx.y + j][threadIdx.x] = s[(size_t)(y0 + threadIdx.y + j) * NN + x];
    __syncthreads();
    int x2 = blockIdx.y * 32 + threadIdx.x;
    int y2 = blockIdx.x * 32;
#pragma unroll
    for (int j = 0; j < 32; j += 8)
        d[(size_t)(y2 + threadIdx.y + j) * NN + x2] = f2bf(t[threadIdx.x][threadIdx.y + j]);
}

// ---- sync primitives (rule #18: sched_barrier after inline waitcnt) ----
#define P_BAR  __builtin_amdgcn_s_barrier()
#define P_LGKM do { asm volatile("s_waitcnt lgkmcnt(0)" ::: "memory"); \
                    __builtin_amdgcn_sched_barrier(0); } while (0)
#define VMW(N) do { asm volatile("s_waitcnt vmcnt(" #N ")" ::: "memory"); \
                    __builtin_amdgcn_sched_barrier(0); } while (0)

#define MF32(a_, b_, c_) __builtin_amdgcn_mfma_f32_32x32x16_bf16(a_, b_, c_, 0, 0, 0)

// one 64x64 chain over BK=32: 4 independent MFMA, then 4 at dep distance 4
#define CHAIN32(A, B, ACC) do { \
    __builtin_amdgcn_s_setprio(1); \
    ACC[0][0] = MF32(A##00, B##00, ACC[0][0]); \
    ACC[0][1] = MF32(A##00, B##10, ACC[0][1]); \
    ACC[1][0] = MF32(A##10, B##00, ACC[1][0]); \
    ACC[1][1] = MF32(A##10, B##10, ACC[1][1]); \
    ACC[0][0] = MF32(A##01, B##01, ACC[0][0]); \
    ACC[0][1] = MF32(A##01, B##11, ACC[0][1]); \
    ACC[1][0] = MF32(A##11, B##01, ACC[1][0]); \
    ACC[1][1] = MF32(A##11, B##11, ACC[1][1]); \
    __builtin_amdgcn_s_setprio(0); \
} while (0)

// K-MAJOR LDS TILE (conflict-free 32x32 reads BY CONSTRUCTION):
// tile = [128 rows][32 k] stored as 16B slot s = kb*128 + row, kb = k/8 (0..3).
// Frag read (lane l, k-slice ks, row-block i): slot (ks*2 + l>>5)*128 + RB+i*32+(l&31)
//   -> lanes 0-31 and 32-63 each cover 32 CONSECUTIVE 16B slots (512B linear
//   run) = all 32 banks swept linearly = 2-way minimal aliasing = free (m136).
// Staged via per-lane global source permutation (gld_lds dest linear, rule #21):
//   thread t, line0 -> slot t     = global (row t&127, k kk + (t>>7)*8)
//   thread t, line1 -> slot t+256 = same row, k + 16.
// D{i}{ks}: i = row-block, ks = k-slice (16 each); lane k = ks*16 + (l>>5)*8.
#define RDF(D, CC, TILE, RB) do { \
    const int rA_ = ((RB) + l31) * 8, rB_ = ((RB) + 32 + l31) * 8; \
    D##00 = *(const bf16x8*)&sm[CC][TILE][kh * 1024 + rA_]; \
    D##01 = *(const bf16x8*)&sm[CC][TILE][(2 + kh) * 1024 + rA_]; \
    D##10 = *(const bf16x8*)&sm[CC][TILE][kh * 1024 + rB_]; \
    D##11 = *(const bf16x8*)&sm[CC][TILE][(2 + kh) * 1024 + rB_]; \
} while (0)

// ------- pass 1 (FUSED, 32x32x16, counted vmcnt): Rtr=NT(Wr,x), Rti=NT(Wi,x) --
__global__ __launch_bounds__(256, 2) void gemm_pass1(
    const u16* __restrict__ Ar, const u16* __restrict__ Ai,
    const u16* __restrict__ B,
    u16* __restrict__ Cr, u16* __restrict__ Ci) {
    __shared__ u16 sm[2][3][4096];   // [buf][Wr,Wi,x], 8KB tiles = 48 KB

    const int brow = blockIdx.y * 128;
    const int bcol = blockIdx.x * 128;

    const int tid  = threadIdx.x;
    const int lane = tid & 63;
    const int wid  = tid >> 6;
    const int wm   = (wid >> 1) * 64;
    const int wn   = (wid & 1) * 64;
    const int l31  = lane & 31;
    const int kh   = lane >> 5;

    f32x16 accr[2][2] = {};
    f32x16 acci[2][2] = {};

    // staging source: row t&127, k-offset (t>>7)*8 (line2: +16)
    const int sr = tid & 127;
    const int sh = (tid >> 7) * 8;
    const size_t aoff = (size_t)(brow + sr) * NN + sh;
    const size_t boff = (size_t)(bcol + sr) * NN + sh;

#define T0(b, kk) gld16(Ar + aoff + (kk),      &sm[b][0][tid * 8])
#define T1(b, kk) gld16(Ar + aoff + (kk) + 16, &sm[b][0][2048 + tid * 8])
#define T2(b, kk) gld16(Ai + aoff + (kk),      &sm[b][1][tid * 8])
#define T3(b, kk) gld16(Ai + aoff + (kk) + 16, &sm[b][1][2048 + tid * 8])
#define T4(b, kk) gld16(B  + boff + (kk),      &sm[b][2][tid * 8])
#define T5(b, kk) gld16(B  + boff + (kk) + 16, &sm[b][2][2048 + tid * 8])

// half-A = {Wr, x} issued P0; half-B = {Wi} issued P1 (R10 scheme, verified)
#define KSTEP1(CC, NB, KN, DOSTG, V0, V1) do { \
    bf16x8 af00, af01, af10, af11, ag00, ag01, ag10, ag11; \
    bf16x8 bx00, bx01, bx10, bx11; \
    RDF(af, CC, 0, wm); RDF(bx, CC, 2, wn); \
    if (DOSTG) { T0(NB, KN); T1(NB, KN); T4(NB, KN); T5(NB, KN); } \
    VMW(V0); P_BAR; P_LGKM; \
    CHAIN32(af, bx, accr); \
    RDF(ag, CC, 1, wm); \
    P_LGKM; \
    if (DOSTG) { T2(NB, KN); T3(NB, KN); } \
    VMW(V1); P_BAR; \
    CHAIN32(ag, bx, acci); \
} while (0)

    T0(0, 0); T1(0, 0); T4(0, 0); T5(0, 0); T2(0, 0); T3(0, 0);
    VMW(2); P_BAR;
    for (int t = 0; t < NN / 32 - 1; ++t) {
        const int cc = t & 1, nb = cc ^ 1;
        KSTEP1(cc, nb, (size_t)(t + 1) * 32, 1, 4, 2);
    }
    KSTEP1(1, 0, 0, 0, 0, 0);

    // C/D 32x32 (verified m74/m101/R7): col=l31, row=(e&3)+8*(e>>2)+4*kh
#pragma unroll
    for (int i = 0; i < 2; i++)
#pragma unroll
        for (int j = 0; j < 2; j++) {
            const int col = bcol + wn + j * 32 + l31;
#pragma unroll
            for (int e = 0; e < 16; e++) {
                const int row = brow + wm + i * 32 + (e & 3) + 8 * (e >> 2) + 4 * kh;
                Cr[(size_t)row * NN + col] = f2bf(accr[i][j][e]);
                Ci[(size_t)row * NN + col] = f2bf(acci[i][j][e]);
            }
        }
}

// ------- pass 2 (FUSED dual complex, 32x32x16, counted vmcnt) ----------------
// C_r[m,n] = sum_k Ar[m,k]Br[n,k] - Ai[m,k]Bi[n,k]
// C_i[m,n] = sum_k Ar[m,k]Bi[n,k] + Ai[m,k]Br[n,k]
__global__ __launch_bounds__(256, 2) void gemm_pass2(
    const u16* __restrict__ Ar, const u16* __restrict__ Ai,
    const u16* __restrict__ Br, const u16* __restrict__ Bi,
    float* __restrict__ Out) {
    __shared__ u16 sm[2][4][4096];   // [buf][Ar,Ai,Br,Bi] = 64 KB

    const int brow = blockIdx.y * 128;
    const int bcol = blockIdx.x * 128;

    const int tid  = threadIdx.x;
    const int lane = tid & 63;
    const int wid  = tid >> 6;
    const int wm   = (wid >> 1) * 64;
    const int wn   = (wid & 1) * 64;
    const int l31  = lane & 31;
    const int kh   = lane >> 5;

    f32x16 accr[2][2] = {};
    f32x16 acci[2][2] = {};

    const int sr = tid & 127;
    const int sh = (tid >> 7) * 8;
    const size_t moff = (size_t)(brow + sr) * NN + sh;
    const size_t noff = (size_t)(bcol + sr) * NN + sh;

#define SL0(b, kk) gld16(Ar + moff + (kk),      &sm[b][0][tid * 8])
#define SL1(b, kk) gld16(Ar + moff + (kk) + 16, &sm[b][0][2048 + tid * 8])
#define SL2(b, kk) gld16(Ai + moff + (kk),      &sm[b][1][tid * 8])
#define SL3(b, kk) gld16(Ai + moff + (kk) + 16, &sm[b][1][2048 + tid * 8])
#define SL4(b, kk) gld16(Br + noff + (kk),      &sm[b][2][tid * 8])
#define SL5(b, kk) gld16(Br + noff + (kk) + 16, &sm[b][2][2048 + tid * 8])
#define SL6(b, kk) gld16(Bi + noff + (kk),      &sm[b][3][tid * 8])
#define SL7(b, kk) gld16(Bi + noff + (kk) + 16, &sm[b][3][2048 + tid * 8])

// half-A = {Ar, Bi} issued P0; half-B = {Br, Ai} (Br first) issued P2.
// V0 guarantees this step's Br; V1 this step's Ai; V2 next step's half-A.
#define KSTEP2(CC, NB, KN, DOSTG, V0, V1, V2) do { \
    bf16x8 ar00, ar01, ar10, ar11, ai00, ai01, ai10, ai11; \
    bf16x8 br00, br01, br10, br11, bi00, bi01, bi10, bi11; \
    /* P0: acci += ar*bi */ \
    RDF(ar, CC, 0, wm); RDF(bi, CC, 3, wn); \
    if (DOSTG) { SL0(NB, KN); SL1(NB, KN); SL6(NB, KN); SL7(NB, KN); } \
    VMW(V0); P_BAR; P_LGKM; \
    CHAIN32(ar, bi, acci); \
    /* P1: accr += ar*br */ \
    RDF(br, CC, 2, wn); \
    P_LGKM; \
    VMW(V1); P_BAR; \
    CHAIN32(ar, br, accr); \
    /* P2: acci += ai*br */ \
    RDF(ai, CC, 1, wm); \
    P_LGKM; \
    if (DOSTG) { SL4(NB, KN); SL5(NB, KN); SL2(NB, KN); SL3(NB, KN); } \
    VMW(V2); P_BAR; \
    CHAIN32(ai, br, acci); \
    /* P3: accr += (-ai)*bi (regs only) */ \
    ai00 = negbf(ai00); ai01 = negbf(ai01); ai10 = negbf(ai10); ai11 = negbf(ai11); \
    CHAIN32(ai, bi, accr); \
} while (0)

    SL0(0, 0); SL1(0, 0); SL6(0, 0); SL7(0, 0);
    SL4(0, 0); SL5(0, 0); SL2(0, 0); SL3(0, 0);
    VMW(4); P_BAR;
    for (int t = 0; t < NN / 32 - 1; ++t) {
        const int cc = t & 1, nb = cc ^ 1;
        KSTEP2(cc, nb, (size_t)(t + 1) * 32, 1, 6, 4, 4);
    }
    KSTEP2(1, 0, 0, 0, 2, 0, 0);

    // C/D 32x32 (verified): col=l31, row=(e&3)+8*(e>>2)+4*kh
#pragma unroll
    for (int i = 0; i < 2; i++)
#pragma unroll
        for (int j = 0; j < 2; j++) {
            const int col = bcol + wn + j * 32 + l31;
#pragma unroll
            for (int e = 0; e < 16; e++) {
                const int row = brow + wm + i * 32 + (e & 3) + 8 * (e >> 2) + 4 * kh;
                Out[(size_t)row * (2 * NN) + col]      = accr[i][j][e];
                Out[(size_t)row * (2 * NN) + NN + col] = acci[i][j][e];
            }
        }
}

extern "C" void kernel_launch(void* const* d_in, const int* in_sizes, int n_in,
                              void* d_out, int out_size, void* d_ws, size_t ws_size,
                              hipStream_t stream) {
    const float* x  = (const float*)d_in[0];
    const float* Wr = (const float*)d_in[1];
    const float* Wi = (const float*)d_in[2];
    float* out = (float*)d_out;

    const size_t SZ = (size_t)NN * NN;
    u16* ws  = (u16*)d_ws;
    u16* xb  = ws;            // slot 0: bf16 x        (later reused: WrT)
    u16* Wrb = ws + SZ;       // slot 1: bf16 W_r      (later reused: WiT)
    u16* Wib = ws + 2 * SZ;   // slot 2: bf16 W_i
    u16* Rtr = ws + 3 * SZ;   // slot 3: R_r^T bf16
    u16* Rti = ws + 4 * SZ;   // slot 4: R_i^T bf16

    // 1) convert inputs to bf16
    cvt_bf16<<<8192, 256, 0, stream>>>(x,  xb);
    cvt_bf16<<<8192, 256, 0, stream>>>(Wr, Wrb);
    cvt_bf16<<<8192, 256, 0, stream>>>(Wi, Wib);

    // 2) fused pass 1: Rt_r = NT(W_r, x), Rt_i = NT(W_i, x)
    gemm_pass1<<<dim3(32, 32), 256, 0, stream>>>(Wrb, Wib, xb, Rtr, Rti);

    // 3) transposed bf16 weights (reuse slots 0,1)
    u16* WrT = xb;
    u16* WiT = Wrb;
    tr_cvt<<<dim3(128, 128), dim3(32, 8), 0, stream>>>(Wr, WrT);
    tr_cvt<<<dim3(128, 128), dim3(32, 8), 0, stream>>>(Wi, WiT);

    // 4) fused pass 2 -> d_out [NN][2*NN]
    gemm_pass2<<<dim3(32, 32), 256, 0, stream>>>(WrT, WiT, Rtr, Rti, out);
}

// Round 12
// 774.732 us; speedup vs baseline: 1.3169x; 1.3169x over previous
//
#include <hip/hip_runtime.h>
#include <hip/hip_bf16.h>

#define NN 4096

typedef unsigned short u16;
using bf16x8 = __attribute__((ext_vector_type(8))) short;
using f32x4  = __attribute__((ext_vector_type(4))) float;
using u32x4  = __attribute__((ext_vector_type(4))) unsigned int;

__device__ inline u16 f2bf(float f) {
    union { float f; unsigned u; } c; c.f = f;
    unsigned r = (c.u + 0x7fffu + ((c.u >> 16) & 1u)) >> 16;
    return (u16)r;
}
__device__ inline float bf2f(u16 b) {
    union { unsigned u; float f; } c; c.u = ((unsigned)b) << 16;
    return c.f;
}

__device__ inline void gld16(const void* g, void* l) {
    __builtin_amdgcn_global_load_lds(
        (const __attribute__((address_space(1))) void*)g,
        (__attribute__((address_space(3))) void*)l, 16, 0, 0);
}

__device__ inline bf16x8 negbf(bf16x8 v) {
    u32x4 u; __builtin_memcpy(&u, &v, 16);
    u ^= 0x80008000u;
    bf16x8 r; __builtin_memcpy(&r, &u, 16);
    return r;
}

// ---------------- f32 -> bf16 convert ----------------
__global__ __launch_bounds__(256) void cvt_bf16(const float* __restrict__ s,
                                                u16* __restrict__ d) {
    size_t i = ((size_t)blockIdx.x * 256 + threadIdx.x) * 8;
    float4 v0 = *(const float4*)(s + i);
    float4 v1 = *(const float4*)(s + i + 4);
    bf16x8 o;
    o[0] = (short)f2bf(v0.x); o[1] = (short)f2bf(v0.y);
    o[2] = (short)f2bf(v0.z); o[3] = (short)f2bf(v0.w);
    o[4] = (short)f2bf(v1.x); o[5] = (short)f2bf(v1.y);
    o[6] = (short)f2bf(v1.z); o[7] = (short)f2bf(v1.w);
    *(bf16x8*)(d + i) = o;
}

// ---------------- transpose + convert: d[m][k] = bf16(s[k][m]) ----------------
__global__ __launch_bounds__(256) void tr_cvt(const float* __restrict__ s,
                                              u16* __restrict__ d) {
    __shared__ float t[32][33];
    int x  = blockIdx.x * 32 + threadIdx.x;
    int y0 = blockIdx.y * 32;
#pragma unroll
    for (int j = 0; j < 32; j += 8)
        t[threadIdx.y + j][threadIdx.x] = s[(size_t)(y0 + threadIdx.y + j) * NN + x];
    __syncthreads();
    int x2 = blockIdx.y * 32 + threadIdx.x;
    int y2 = blockIdx.x * 32;
#pragma unroll
    for (int j = 0; j < 32; j += 8)
        d[(size_t)(y2 + threadIdx.y + j) * NN + x2] = f2bf(t[threadIdx.x][threadIdx.y + j]);
}

// ---------------- bf16 elementwise sum: d = a + b ----------------
__global__ __launch_bounds__(256) void presum(const u16* __restrict__ a,
                                              const u16* __restrict__ b,
                                              u16* __restrict__ d) {
    size_t i = ((size_t)blockIdx.x * 256 + threadIdx.x) * 8;
    bf16x8 va = *(const bf16x8*)(a + i);
    bf16x8 vb = *(const bf16x8*)(b + i);
    bf16x8 o;
#pragma unroll
    for (int j = 0; j < 8; j++)
        o[j] = (short)f2bf(bf2f((u16)va[j]) + bf2f((u16)vb[j]));
    *(bf16x8*)(d + i) = o;
}

// ---------------- Karatsuba combine (in place on out) ----------------
// outL holds M1, outR holds M3, M2 in ws.  Cr = M1-M2 ; Ci = M3-M1-M2.
__global__ __launch_bounds__(256) void combine(float* __restrict__ out,
                                               const float* __restrict__ M2) {
    size_t i = ((size_t)blockIdx.x * 256 + threadIdx.x) * 4;
    size_t m = i >> 12, n = i & 4095;
    float4 v1 = *(float4*)(out + m * 8192 + n);
    float4 v3 = *(float4*)(out + m * 8192 + 4096 + n);
    float4 v2 = *(const float4*)(M2 + m * 4096 + n);
    float4 cr, ci;
    cr.x = v1.x - v2.x; ci.x = v3.x - v1.x - v2.x;
    cr.y = v1.y - v2.y; ci.y = v3.y - v1.y - v2.y;
    cr.z = v1.z - v2.z; ci.z = v3.z - v1.z - v2.z;
    cr.w = v1.w - v2.w; ci.w = v3.w - v1.w - v2.w;
    *(float4*)(out + m * 8192 + n) = cr;
    *(float4*)(out + m * 8192 + 4096 + n) = ci;
}

// ---- sync primitives (rule #18: sched_barrier after inline waitcnt) ----
#define P_BAR  __builtin_amdgcn_s_barrier()
#define P_SCH  __builtin_amdgcn_sched_barrier(0)
#define P_LGKM do { asm volatile("s_waitcnt lgkmcnt(0)" ::: "memory"); \
                    __builtin_amdgcn_sched_barrier(0); } while (0)
#define VMW(N) do { asm volatile("s_waitcnt vmcnt(" #N ")" ::: "memory"); \
                    __builtin_amdgcn_sched_barrier(0); } while (0)

#define CHAIN(AF, BF, ACC) do { \
    __builtin_amdgcn_s_setprio(1); \
    _Pragma("unroll") \
    for (int i_ = 0; i_ < 4; i_++) \
        _Pragma("unroll") \
        for (int j_ = 0; j_ < 4; j_++) \
            ACC[i_][j_] = __builtin_amdgcn_mfma_f32_16x16x32_bf16(AF[i_], BF[j_], ACC[i_][j_], 0, 0, 0); \
    __builtin_amdgcn_s_setprio(0); \
} while (0)

#define RD4(DST, CC, TILE, BASE) do { \
    _Pragma("unroll") \
    for (int i_ = 0; i_ < 4; i_++) \
        DST[i_] = *(const bf16x8*)&sm[CC][TILE][((BASE) + i_ * 16 + rl) * 32 + kg]; \
} while (0)

// LDS swizzle (proven R3-R10, 0 conflicts): physical 16B-block p at row r
// holds logical p ^ ((r>>1)&3); staged via inverse-permuted GLOBAL source
// (gld_lds dest linear, rule #21); read back with same XOR.

// ---------------- pass 1 (FUSED, R10-verified): Rtr=NT(Wr,x), Rti=NT(Wi,x) ---
__global__ __launch_bounds__(256, 2) void gemm_pass1(
    const u16* __restrict__ Ar, const u16* __restrict__ Ai,
    const u16* __restrict__ B,
    u16* __restrict__ Cr, u16* __restrict__ Ci) {
    __shared__ u16 sm[2][3][4096];

    const int brow = blockIdx.y * 128;
    const int bcol = blockIdx.x * 128;

    const int tid  = threadIdx.x;
    const int lane = tid & 63;
    const int wid  = tid >> 6;
    const int wm   = (wid >> 1) * 64;
    const int wn   = (wid & 1) * 64;

    f32x4 accr[4][4] = {};
    f32x4 acci[4][4] = {};

    const int r0 = tid >> 2;
    const int lb = (tid & 3) ^ ((r0 >> 1) & 3);
    const size_t aoff0 = (size_t)(brow + r0) * NN + lb * 8;
    const size_t aoff1 = aoff0 + (size_t)64 * NN;
    const size_t boff0 = (size_t)(bcol + r0) * NN + lb * 8;
    const size_t boff1 = boff0 + (size_t)64 * NN;
    const int rl = lane & 15;
    const int kg = ((lane >> 4) ^ ((rl >> 1) & 3)) * 8;

#define T0(b, kk) gld16(Ar + aoff0 + (kk), &sm[b][0][tid * 8])
#define T1(b, kk) gld16(Ar + aoff1 + (kk), &sm[b][0][2048 + tid * 8])
#define T2(b, kk) gld16(Ai + aoff0 + (kk), &sm[b][1][tid * 8])
#define T3(b, kk) gld16(Ai + aoff1 + (kk), &sm[b][1][2048 + tid * 8])
#define T4(b, kk) gld16(B  + boff0 + (kk), &sm[b][2][tid * 8])
#define T5(b, kk) gld16(B  + boff1 + (kk), &sm[b][2][2048 + tid * 8])

#define KSTEP1(CC, NB, KN, DOSTG, V0, V1) do { \
    bf16x8 af[4], ag[4], bb[4]; \
    RD4(af, CC, 0, wm); RD4(bb, CC, 2, wn); \
    if (DOSTG) { T0(NB, KN); T1(NB, KN); T4(NB, KN); T5(NB, KN); } \
    VMW(V0); P_BAR; P_LGKM; \
    CHAIN(af, bb, accr); \
    RD4(ag, CC, 1, wm); \
    P_LGKM; \
    if (DOSTG) { T2(NB, KN); T3(NB, KN); } \
    VMW(V1); P_BAR; \
    CHAIN(ag, bb, acci); \
} while (0)

    T0(0, 0); T1(0, 0); T4(0, 0); T5(0, 0); T2(0, 0); T3(0, 0);
    VMW(2); P_BAR;
    for (int t = 0; t < NN / 32 - 1; ++t) {
        const int cc = t & 1, nb = cc ^ 1;
        KSTEP1(cc, nb, (size_t)(t + 1) * 32, 1, 4, 2);
    }
    KSTEP1(1, 0, 0, 0, 0, 0);

    const int rg = (lane >> 4) * 4;
#pragma unroll
    for (int i = 0; i < 4; i++)
#pragma unroll
        for (int j = 0; j < 4; j++) {
            int col = bcol + wn + j * 16 + rl;
#pragma unroll
            for (int r = 0; r < 4; r++) {
                int row = brow + wm + i * 16 + rg + r;
                Cr[(size_t)row * NN + col] = f2bf(accr[i][j][r]);
                Ci[(size_t)row * NN + col] = f2bf(acci[i][j][r]);
            }
        }
}

// ========== 256x256-tile, BK=32, 4-LDS-buffer deep-pipelined NT GEMM =========
// C[i][j] = sum_k A[i][k]*B[j][k]. 512 thr = 8 waves (2M x 4N), wave tile
// 128x64. LDS = 4 buf x (A,B) x [256 rows][32 k] bf16 = 128 KB. Stage at
// step t targets buf (t+2)&3 (2 tiles deep) -> NO overwrite hazard window;
// vmcnt(4) at phase-top only (never 0 until tail); 1 barrier + 2 lgkm /step.
#define SGA(NB, KN) do { \
    gld16(A + aoff0 + (KN), &sm2[NB][0][tid * 8]); \
    gld16(A + aoff1 + (KN), &sm2[NB][0][4096 + tid * 8]); \
} while (0)
#define SGB(NB, KN) do { \
    gld16(Bp + boff0 + (KN), &sm2[NB][1][tid * 8]); \
    gld16(Bp + boff1 + (KN), &sm2[NB][1][4096 + tid * 8]); \
} while (0)

#define K256(CB, NB, KN, DOSTG, V) do { \
    bf16x8 a[4], b[4], c[4]; \
    VMW(V); P_BAR; P_SCH; \
    /* P0: rowfrags 0-3 */ \
    _Pragma("unroll") \
    for (int i_ = 0; i_ < 4; i_++) \
        a[i_] = *(const bf16x8*)&sm2[CB][0][(wr128 + i_ * 16 + rl) * 32 + kg]; \
    _Pragma("unroll") \
    for (int j_ = 0; j_ < 4; j_++) \
        b[j_] = *(const bf16x8*)&sm2[CB][1][(wc64 + j_ * 16 + rl) * 32 + kg]; \
    if (DOSTG) SGA(NB, KN); \
    P_LGKM; \
    __builtin_amdgcn_s_setprio(1); \
    _Pragma("unroll") \
    for (int i_ = 0; i_ < 4; i_++) \
        _Pragma("unroll") \
        for (int j_ = 0; j_ < 4; j_++) \
            acc[i_][j_] = __builtin_amdgcn_mfma_f32_16x16x32_bf16(a[i_], b[j_], acc[i_][j_], 0, 0, 0); \
    __builtin_amdgcn_s_setprio(0); \
    /* P1: rowfrags 4-7 */ \
    _Pragma("unroll") \
    for (int i_ = 0; i_ < 4; i_++) \
        c[i_] = *(const bf16x8*)&sm2[CB][0][(wr128 + 64 + i_ * 16 + rl) * 32 + kg]; \
    if (DOSTG) SGB(NB, KN); \
    P_LGKM; \
    __builtin_amdgcn_s_setprio(1); \
    _Pragma("unroll") \
    for (int i_ = 0; i_ < 4; i_++) \
        _Pragma("unroll") \
        for (int j_ = 0; j_ < 4; j_++) \
            acc[4 + i_][j_] = __builtin_amdgcn_mfma_f32_16x16x32_bf16(c[i_], b[j_], acc[4 + i_][j_], 0, 0, 0); \
    __builtin_amdgcn_s_setprio(0); \
} while (0)

template <bool F32OUT>
__global__ __launch_bounds__(512, 2) void gemm256k(
    const u16* __restrict__ A, const u16* __restrict__ Bp,
    u16* __restrict__ Cb, float* __restrict__ Cf, int cstride) {
    __shared__ u16 sm2[4][2][8192];   // [buf][A,B][256*32] = 128 KB

    const int brow = blockIdx.y * 256;
    const int bcol = blockIdx.x * 256;

    const int tid  = threadIdx.x;
    const int lane = tid & 63;
    const int wid  = tid >> 6;
    const int wr128 = (wid >> 2) * 128;  // 2 M-waves
    const int wc64  = (wid & 3) * 64;    // 4 N-waves
    const int rl = lane & 15;
    const int kq = lane >> 4;
    const int kg = (kq ^ ((rl >> 1) & 3)) * 8;

    // staging: thread t -> rows r0 and r0+128, 16B-block t&3, logical src
    // block lb = (t&3)^((r0>>1)&3)  (key invariant under row+128)
    const int r0 = tid >> 2;
    const int lb = (tid & 3) ^ ((r0 >> 1) & 3);
    const size_t aoff0 = (size_t)(brow + r0) * NN + lb * 8;
    const size_t aoff1 = aoff0 + (size_t)128 * NN;
    const size_t boff0 = (size_t)(bcol + r0) * NN + lb * 8;
    const size_t boff1 = boff0 + (size_t)128 * NN;

    f32x4 acc[8][4] = {};

    // prologue: tiles 0 -> buf0, 1 -> buf1 (8 lines)
    SGA(0, 0); SGB(0, 0); SGA(1, 32); SGB(1, 32);

    // main: t = 0..123 in 4x-unrolled blocks (compile-time buf indices)
    for (int tb = 0; tb < 31; ++tb) {
        const size_t k0 = (size_t)tb * 128;
        K256(0, 2, k0 + 64,  1, 4);
        K256(1, 3, k0 + 96,  1, 4);
        K256(2, 0, k0 + 128, 1, 4);
        K256(3, 1, k0 + 160, 1, 4);
    }
    K256(0, 2, 4032, 1, 4);   // t=124 stages tile 126
    K256(1, 3, 4064, 1, 4);   // t=125 stages tile 127
    K256(2, 0, 0,    0, 4);   // t=126
    K256(3, 0, 0,    0, 0);   // t=127 (final drain)

    // epilogue (verified R5): col = bcol + wc*64 + fc*16 + rl,
    // row = brow + wr*128 + fr*16 + kq*4 + e
    const int rg = kq * 4;
#pragma unroll
    for (int fr = 0; fr < 8; fr++)
#pragma unroll
        for (int fc = 0; fc < 4; fc++) {
            const int col = bcol + wc64 + fc * 16 + rl;
#pragma unroll
            for (int e = 0; e < 4; e++) {
                const int row = brow + wr128 + fr * 16 + rg + e;
                if (F32OUT)
                    Cf[(size_t)row * cstride + col] = acc[fr][fc][e];
                else
                    Cb[(size_t)row * NN + col] = f2bf(acc[fr][fc][e]);
            }
        }
}

extern "C" void kernel_launch(void* const* d_in, const int* in_sizes, int n_in,
                              void* d_out, int out_size, void* d_ws, size_t ws_size,
                              hipStream_t stream) {
    const float* x  = (const float*)d_in[0];
    const float* Wr = (const float*)d_in[1];
    const float* Wi = (const float*)d_in[2];
    float* out = (float*)d_out;

    const size_t SZ = (size_t)NN * NN;
    u16* ws = (u16*)d_ws;
    u16* s0 = ws;            // xb   -> WrT
    u16* s1 = ws + SZ;       // Wrb  -> WiT
    u16* s2 = ws + 2 * SZ;   // Wib  -> S_A ; later (s2,s3) = M2 f32
    u16* s3 = ws + 3 * SZ;   // Rtr
    u16* s4 = ws + 4 * SZ;   // Rti
    u16* s5 = ws + 5 * SZ;   // S_B
    float* M2 = (float*)s2;  // 64MB f32 over s2+s3 (dead by then; R4/R5-verified)

    // 1) convert inputs to bf16
    cvt_bf16<<<8192, 256, 0, stream>>>(x,  s0);
    cvt_bf16<<<8192, 256, 0, stream>>>(Wr, s1);
    cvt_bf16<<<8192, 256, 0, stream>>>(Wi, s2);

    // 2) fused pass 1 (R10-verified): Rtr = NT(Wr, x), Rti = NT(Wi, x)
    gemm_pass1<<<dim3(32, 32), 256, 0, stream>>>(s1, s2, s0, s3, s4);

    // 3) transposed weights (s0,s1 dead), Karatsuba presums
    tr_cvt<<<dim3(128, 128), dim3(32, 8), 0, stream>>>(Wr, s0);   // WrT
    tr_cvt<<<dim3(128, 128), dim3(32, 8), 0, stream>>>(Wi, s1);   // WiT
    presum<<<8192, 256, 0, stream>>>(s0, s1, s2);                 // S_A = WrT+WiT
    presum<<<8192, 256, 0, stream>>>(s3, s4, s5);                 // S_B = Rtr+Rti

    // 4) pass 2 via Karatsuba (M3 before M1 before M2 for slot reuse)
    gemm256k<true><<<dim3(16, 16), 512, 0, stream>>>(s2, s5, nullptr, out + NN, 2 * NN); // M3
    gemm256k<true><<<dim3(16, 16), 512, 0, stream>>>(s0, s3, nullptr, out,      2 * NN); // M1
    gemm256k<true><<<dim3(16, 16), 512, 0, stream>>>(s1, s4, nullptr, M2,       NN);     // M2

    // 5) combine: Cr = M1-M2, Ci = M3-M1-M2
    combine<<<16384, 256, 0, stream>>>(out, M2);
}

// Round 13
// 774.521 us; speedup vs baseline: 1.3172x; 1.0003x over previous
//
#include <hip/hip_runtime.h>
#include <hip/hip_bf16.h>

#define NN 4096

typedef unsigned short u16;
using bf16x8 = __attribute__((ext_vector_type(8))) short;
using f32x4  = __attribute__((ext_vector_type(4))) float;

__device__ inline u16 f2bf(float f) {
    union { float f; unsigned u; } c; c.f = f;
    unsigned r = (c.u + 0x7fffu + ((c.u >> 16) & 1u)) >> 16;
    return (u16)r;
}
__device__ inline float bf2f(u16 b) {
    union { unsigned u; float f; } c; c.u = ((unsigned)b) << 16;
    return c.f;
}

__device__ inline void gld16(const void* g, void* l) {
    __builtin_amdgcn_global_load_lds(
        (const __attribute__((address_space(1))) void*)g,
        (__attribute__((address_space(3))) void*)l, 16, 0, 0);
}

// ---------------- f32 -> bf16 convert ----------------
__global__ __launch_bounds__(256) void cvt_bf16(const float* __restrict__ s,
                                                u16* __restrict__ d) {
    size_t i = ((size_t)blockIdx.x * 256 + threadIdx.x) * 8;
    float4 v0 = *(const float4*)(s + i);
    float4 v1 = *(const float4*)(s + i + 4);
    bf16x8 o;
    o[0] = (short)f2bf(v0.x); o[1] = (short)f2bf(v0.y);
    o[2] = (short)f2bf(v0.z); o[3] = (short)f2bf(v0.w);
    o[4] = (short)f2bf(v1.x); o[5] = (short)f2bf(v1.y);
    o[6] = (short)f2bf(v1.z); o[7] = (short)f2bf(v1.w);
    *(bf16x8*)(d + i) = o;
}

// ------- fused weight prep: WrT, WiT, S_A = WrT + WiT in one pass ----------
__global__ __launch_bounds__(256) void wprep(const float* __restrict__ Wr,
                                             const float* __restrict__ Wi,
                                             u16* __restrict__ WrT,
                                             u16* __restrict__ WiT,
                                             u16* __restrict__ SA) {
    __shared__ float tr[32][33], ti[32][33];
    int x  = blockIdx.x * 32 + threadIdx.x;
    int y0 = blockIdx.y * 32;
#pragma unroll
    for (int j = 0; j < 32; j += 8) {
        tr[threadIdx.y + j][threadIdx.x] = Wr[(size_t)(y0 + threadIdx.y + j) * NN + x];
        ti[threadIdx.y + j][threadIdx.x] = Wi[(size_t)(y0 + threadIdx.y + j) * NN + x];
    }
    __syncthreads();
    int x2 = blockIdx.y * 32 + threadIdx.x;
    int y2 = blockIdx.x * 32;
#pragma unroll
    for (int j = 0; j < 32; j += 8) {
        float a = tr[threadIdx.x][threadIdx.y + j];
        float b = ti[threadIdx.x][threadIdx.y + j];
        size_t o = (size_t)(y2 + threadIdx.y + j) * NN + x2;
        WrT[o] = f2bf(a);
        WiT[o] = f2bf(b);
        SA[o]  = f2bf(a + b);
    }
}

// ---------------- bf16 elementwise sum: d = a + b (S_B) ----------------
__global__ __launch_bounds__(256) void presum(const u16* __restrict__ a,
                                              const u16* __restrict__ b,
                                              u16* __restrict__ d) {
    size_t i = ((size_t)blockIdx.x * 256 + threadIdx.x) * 8;
    bf16x8 va = *(const bf16x8*)(a + i);
    bf16x8 vb = *(const bf16x8*)(b + i);
    bf16x8 o;
#pragma unroll
    for (int j = 0; j < 8; j++)
        o[j] = (short)f2bf(bf2f((u16)va[j]) + bf2f((u16)vb[j]));
    *(bf16x8*)(d + i) = o;
}

// ---- sync primitives (rule #18: sched_barrier after inline waitcnt) ----
#define P_BAR  __builtin_amdgcn_s_barrier()
#define P_SCH  __builtin_amdgcn_sched_barrier(0)
#define P_LGKM do { asm volatile("s_waitcnt lgkmcnt(0)" ::: "memory"); \
                    __builtin_amdgcn_sched_barrier(0); } while (0)
#define VMW(N) do { asm volatile("s_waitcnt vmcnt(" #N ")" ::: "memory"); \
                    __builtin_amdgcn_sched_barrier(0); } while (0)

// ========== 256x256-tile, BK=32, 4-LDS-buffer deep-pipelined NT GEMM =========
// (R12-verified structure.) C[i][j] = sum_k A[i][k]*B[j][k]. 512 thr = 8 waves
// (2M x 4N), wave tile 128x64. LDS = 4 buf x (A,B) x [256][32] bf16 = 128 KB.
// Stage at step t targets buf (t+2)&3; vmcnt(4) at phase-top (never 0 until
// tail); 1 barrier + 2 lgkm per step. LDS swizzle: phys 16B-block p at row r
// holds logical p^((r>>1)&3), via inverse-permuted global source (rule #21).
#define SGA(NB, KN) do { \
    gld16(A + aoff0 + (KN), &sm2[NB][0][tid * 8]); \
    gld16(A + aoff1 + (KN), &sm2[NB][0][4096 + tid * 8]); \
} while (0)
#define SGB(NB, KN) do { \
    gld16(Bp + boff0 + (KN), &sm2[NB][1][tid * 8]); \
    gld16(Bp + boff1 + (KN), &sm2[NB][1][4096 + tid * 8]); \
} while (0)

#define K256(CB, NB, KN, DOSTG, V) do { \
    bf16x8 a[4], b[4], c[4]; \
    VMW(V); P_BAR; P_SCH; \
    _Pragma("unroll") \
    for (int i_ = 0; i_ < 4; i_++) \
        a[i_] = *(const bf16x8*)&sm2[CB][0][(wr128 + i_ * 16 + rl) * 32 + kg]; \
    _Pragma("unroll") \
    for (int j_ = 0; j_ < 4; j_++) \
        b[j_] = *(const bf16x8*)&sm2[CB][1][(wc64 + j_ * 16 + rl) * 32 + kg]; \
    if (DOSTG) SGA(NB, KN); \
    P_LGKM; \
    __builtin_amdgcn_s_setprio(1); \
    _Pragma("unroll") \
    for (int i_ = 0; i_ < 4; i_++) \
        _Pragma("unroll") \
        for (int j_ = 0; j_ < 4; j_++) \
            acc[i_][j_] = __builtin_amdgcn_mfma_f32_16x16x32_bf16(a[i_], b[j_], acc[i_][j_], 0, 0, 0); \
    __builtin_amdgcn_s_setprio(0); \
    _Pragma("unroll") \
    for (int i_ = 0; i_ < 4; i_++) \
        c[i_] = *(const bf16x8*)&sm2[CB][0][(wr128 + 64 + i_ * 16 + rl) * 32 + kg]; \
    if (DOSTG) SGB(NB, KN); \
    P_LGKM; \
    __builtin_amdgcn_s_setprio(1); \
    _Pragma("unroll") \
    for (int i_ = 0; i_ < 4; i_++) \
        _Pragma("unroll") \
        for (int j_ = 0; j_ < 4; j_++) \
            acc[4 + i_][j_] = __builtin_amdgcn_mfma_f32_16x16x32_bf16(c[i_], b[j_], acc[4 + i_][j_], 0, 0, 0); \
    __builtin_amdgcn_s_setprio(0); \
} while (0)

// OM: 0 = bf16 out (stride NN), 1 = f32 out (stride cs), 2 = f32 Karatsuba
// combine (Cf = out base, cs = 8192; reads M1 = Cf[r][c], M3 = Cf[r][4096+c],
// writes Cr = M1 - acc, Ci = M3 - M1 - acc).
template <int OM>
__global__ __launch_bounds__(512, 2) void gemm256k(
    const u16* __restrict__ A, const u16* __restrict__ Bp,
    u16* __restrict__ Cb, float* __restrict__ Cf, int cs) {
    __shared__ u16 sm2[4][2][8192];

    const int brow = blockIdx.y * 256;
    const int bcol = blockIdx.x * 256;

    const int tid  = threadIdx.x;
    const int lane = tid & 63;
    const int wid  = tid >> 6;
    const int wr128 = (wid >> 2) * 128;
    const int wc64  = (wid & 3) * 64;
    const int rl = lane & 15;
    const int kq = lane >> 4;
    const int kg = (kq ^ ((rl >> 1) & 3)) * 8;

    const int r0 = tid >> 2;
    const int lb = (tid & 3) ^ ((r0 >> 1) & 3);
    const size_t aoff0 = (size_t)(brow + r0) * NN + lb * 8;
    const size_t aoff1 = aoff0 + (size_t)128 * NN;
    const size_t boff0 = (size_t)(bcol + r0) * NN + lb * 8;
    const size_t boff1 = boff0 + (size_t)128 * NN;

    f32x4 acc[8][4] = {};

    SGA(0, 0); SGB(0, 0); SGA(1, 32); SGB(1, 32);

    for (int tb = 0; tb < 31; ++tb) {
        const size_t k0 = (size_t)tb * 128;
        K256(0, 2, k0 + 64,  1, 4);
        K256(1, 3, k0 + 96,  1, 4);
        K256(2, 0, k0 + 128, 1, 4);
        K256(3, 1, k0 + 160, 1, 4);
    }
    K256(0, 2, 4032, 1, 4);
    K256(1, 3, 4064, 1, 4);
    K256(2, 0, 0,    0, 4);
    K256(3, 0, 0,    0, 0);

    const int rg = kq * 4;
#pragma unroll
    for (int fr = 0; fr < 8; fr++)
#pragma unroll
        for (int fc = 0; fc < 4; fc++) {
            const int col = bcol + wc64 + fc * 16 + rl;
#pragma unroll
            for (int e = 0; e < 4; e++) {
                const int row = brow + wr128 + fr * 16 + rg + e;
                if (OM == 0) {
                    Cb[(size_t)row * NN + col] = f2bf(acc[fr][fc][e]);
                } else if (OM == 1) {
                    Cf[(size_t)row * cs + col] = acc[fr][fc][e];
                } else {
                    float m2 = acc[fr][fc][e];
                    float v1 = Cf[(size_t)row * cs + col];
                    float v3 = Cf[(size_t)row * cs + 4096 + col];
                    Cf[(size_t)row * cs + col]        = v1 - m2;
                    Cf[(size_t)row * cs + 4096 + col] = v3 - v1 - m2;
                }
            }
        }
}

extern "C" void kernel_launch(void* const* d_in, const int* in_sizes, int n_in,
                              void* d_out, int out_size, void* d_ws, size_t ws_size,
                              hipStream_t stream) {
    const float* x  = (const float*)d_in[0];
    const float* Wr = (const float*)d_in[1];
    const float* Wi = (const float*)d_in[2];
    float* out = (float*)d_out;

    const size_t SZ = (size_t)NN * NN;
    u16* ws = (u16*)d_ws;
    u16* s0 = ws;            // xb   -> WrT
    u16* s1 = ws + SZ;       // Wrb  -> WiT
    u16* s2 = ws + 2 * SZ;   // Wib  -> S_A
    u16* s3 = ws + 3 * SZ;   // Rtr
    u16* s4 = ws + 4 * SZ;   // Rti
    u16* s5 = ws + 5 * SZ;   // S_B

    // 1) convert inputs to bf16
    cvt_bf16<<<8192, 256, 0, stream>>>(x,  s0);
    cvt_bf16<<<8192, 256, 0, stream>>>(Wr, s1);
    cvt_bf16<<<8192, 256, 0, stream>>>(Wi, s2);

    // 2) pass 1 on the deep-pipelined 256^2 kernel (bf16 out):
    //    Rtr = NT(Wr, x), Rti = NT(Wi, x)
    gemm256k<0><<<dim3(16, 16), 512, 0, stream>>>(s1, s0, s3, nullptr, 0);
    gemm256k<0><<<dim3(16, 16), 512, 0, stream>>>(s2, s0, s4, nullptr, 0);

    // 3) weight prep (one pass): WrT -> s0, WiT -> s1, S_A = WrT+WiT -> s2
    //    (s0,s1,s2 all dead after step 2)
    wprep<<<dim3(128, 128), dim3(32, 8), 0, stream>>>(Wr, Wi, s0, s1, s2);
    //    S_B = Rtr + Rti -> s5
    presum<<<8192, 256, 0, stream>>>(s3, s4, s5);

    // 4) pass 2 via Karatsuba on gemm256k:
    //    M3 = NT(S_A, S_B) -> out right half ; M1 = NT(WrT, Rtr) -> out left;
    //    M2 = NT(WiT, Rti) fused with combine: Cr = M1-M2, Ci = M3-M1-M2.
    gemm256k<1><<<dim3(16, 16), 512, 0, stream>>>(s2, s5, nullptr, out + NN, 2 * NN); // M3
    gemm256k<1><<<dim3(16, 16), 512, 0, stream>>>(s0, s3, nullptr, out,      2 * NN); // M1
    gemm256k<2><<<dim3(16, 16), 512, 0, stream>>>(s1, s4, nullptr, out,      2 * NN); // M2+combine
}

// Round 14
// 740.114 us; speedup vs baseline: 1.3785x; 1.0465x over previous
//
#include <hip/hip_runtime.h>
#include <hip/hip_bf16.h>

#define NN 4096

typedef unsigned short u16;
using bf16x8 = __attribute__((ext_vector_type(8))) short;
using f32x4  = __attribute__((ext_vector_type(4))) float;

__device__ inline u16 f2bf(float f) {
    union { float f; unsigned u; } c; c.f = f;
    unsigned r = (c.u + 0x7fffu + ((c.u >> 16) & 1u)) >> 16;
    return (u16)r;
}
__device__ inline float bf2f(u16 b) {
    union { unsigned u; float f; } c; c.u = ((unsigned)b) << 16;
    return c.f;
}

__device__ inline void gld16(const void* g, void* l) {
    __builtin_amdgcn_global_load_lds(
        (const __attribute__((address_space(1))) void*)g,
        (__attribute__((address_space(3))) void*)l, 16, 0, 0);
}

// ---------------- f32 -> bf16 convert ----------------
__global__ __launch_bounds__(256) void cvt_bf16(const float* __restrict__ s,
                                                u16* __restrict__ d) {
    size_t i = ((size_t)blockIdx.x * 256 + threadIdx.x) * 8;
    float4 v0 = *(const float4*)(s + i);
    float4 v1 = *(const float4*)(s + i + 4);
    bf16x8 o;
    o[0] = (short)f2bf(v0.x); o[1] = (short)f2bf(v0.y);
    o[2] = (short)f2bf(v0.z); o[3] = (short)f2bf(v0.w);
    o[4] = (short)f2bf(v1.x); o[5] = (short)f2bf(v1.y);
    o[6] = (short)f2bf(v1.z); o[7] = (short)f2bf(v1.w);
    *(bf16x8*)(d + i) = o;
}

// ------- fused weight prep: WrT, WiT, S_A = WrT + WiT in one pass ----------
__global__ __launch_bounds__(256) void wprep(const float* __restrict__ Wr,
                                             const float* __restrict__ Wi,
                                             u16* __restrict__ WrT,
                                             u16* __restrict__ WiT,
                                             u16* __restrict__ SA) {
    __shared__ float tr[32][33], ti[32][33];
    int x  = blockIdx.x * 32 + threadIdx.x;
    int y0 = blockIdx.y * 32;
#pragma unroll
    for (int j = 0; j < 32; j += 8) {
        tr[threadIdx.y + j][threadIdx.x] = Wr[(size_t)(y0 + threadIdx.y + j) * NN + x];
        ti[threadIdx.y + j][threadIdx.x] = Wi[(size_t)(y0 + threadIdx.y + j) * NN + x];
    }
    __syncthreads();
    int x2 = blockIdx.y * 32 + threadIdx.x;
    int y2 = blockIdx.x * 32;
#pragma unroll
    for (int j = 0; j < 32; j += 8) {
        float a = tr[threadIdx.x][threadIdx.y + j];
        float b = ti[threadIdx.x][threadIdx.y + j];
        size_t o = (size_t)(y2 + threadIdx.y + j) * NN + x2;
        WrT[o] = f2bf(a);
        WiT[o] = f2bf(b);
        SA[o]  = f2bf(a + b);
    }
}

// ---------------- bf16 elementwise sum: d = a + b (S_B) ----------------
__global__ __launch_bounds__(256) void presum(const u16* __restrict__ a,
                                              const u16* __restrict__ b,
                                              u16* __restrict__ d) {
    size_t i = ((size_t)blockIdx.x * 256 + threadIdx.x) * 8;
    bf16x8 va = *(const bf16x8*)(a + i);
    bf16x8 vb = *(const bf16x8*)(b + i);
    bf16x8 o;
#pragma unroll
    for (int j = 0; j < 8; j++)
        o[j] = (short)f2bf(bf2f((u16)va[j]) + bf2f((u16)vb[j]));
    *(bf16x8*)(d + i) = o;
}

// ---------------- Karatsuba combine (separate, streaming, R11-verified) ------
// outL holds M1, outR holds M3, M2 in ws.  Cr = M1-M2 ; Ci = M3-M1-M2.
__global__ __launch_bounds__(256) void combine(float* __restrict__ out,
                                               const float* __restrict__ M2) {
    size_t i = ((size_t)blockIdx.x * 256 + threadIdx.x) * 4;
    size_t m = i >> 12, n = i & 4095;
    float4 v1 = *(float4*)(out + m * 8192 + n);
    float4 v3 = *(float4*)(out + m * 8192 + 4096 + n);
    float4 v2 = *(const float4*)(M2 + m * 4096 + n);
    float4 cr, ci;
    cr.x = v1.x - v2.x; ci.x = v3.x - v1.x - v2.x;
    cr.y = v1.y - v2.y; ci.y = v3.y - v1.y - v2.y;
    cr.z = v1.z - v2.z; ci.z = v3.z - v1.z - v2.z;
    cr.w = v1.w - v2.w; ci.w = v3.w - v1.w - v2.w;
    *(float4*)(out + m * 8192 + n) = cr;
    *(float4*)(out + m * 8192 + 4096 + n) = ci;
}

// ---- sync primitives (rule #18: sched_barrier after inline waitcnt) ----
#define P_BAR  __builtin_amdgcn_s_barrier()
#define P_SCH  __builtin_amdgcn_sched_barrier(0)
#define P_LGKM do { asm volatile("s_waitcnt lgkmcnt(0)" ::: "memory"); \
                    __builtin_amdgcn_sched_barrier(0); } while (0)
#define VMW(N) do { asm volatile("s_waitcnt vmcnt(" #N ")" ::: "memory"); \
                    __builtin_amdgcn_sched_barrier(0); } while (0)

// ========== 256x256-tile, BK=32, 4-LDS-buffer deep-pipelined NT GEMM =========
// (R12/R13-verified.) C[i][j] = sum_k A[i][k]*B[j][k]. 512 thr = 8 waves
// (2M x 4N), wave tile 128x64. LDS = 4 buf x (A,B) x [256][32] bf16 = 128 KB
// (1 block/CU). Stage at step t targets buf (t+2)&3; vmcnt(4) at phase-top
// (never 0 until tail); 1 barrier + 2 lgkm per step. LDS swizzle: phys
// 16B-block p at row r holds logical p^((r>>1)&3), via inverse-permuted
// global source (rule #21).
#define SGA(NB, KN) do { \
    gld16(A + aoff0 + (KN), &sm2[NB][0][tid * 8]); \
    gld16(A + aoff1 + (KN), &sm2[NB][0][4096 + tid * 8]); \
} while (0)
#define SGB(NB, KN) do { \
    gld16(Bp + boff0 + (KN), &sm2[NB][1][tid * 8]); \
    gld16(Bp + boff1 + (KN), &sm2[NB][1][4096 + tid * 8]); \
} while (0)

#define K256(CB, NB, KN, DOSTG, V) do { \
    bf16x8 a[4], b[4], c[4]; \
    VMW(V); P_BAR; P_SCH; \
    _Pragma("unroll") \
    for (int i_ = 0; i_ < 4; i_++) \
        a[i_] = *(const bf16x8*)&sm2[CB][0][(wr128 + i_ * 16 + rl) * 32 + kg]; \
    _Pragma("unroll") \
    for (int j_ = 0; j_ < 4; j_++) \
        b[j_] = *(const bf16x8*)&sm2[CB][1][(wc64 + j_ * 16 + rl) * 32 + kg]; \
    if (DOSTG) SGA(NB, KN); \
    P_LGKM; \
    __builtin_amdgcn_s_setprio(1); \
    _Pragma("unroll") \
    for (int i_ = 0; i_ < 4; i_++) \
        _Pragma("unroll") \
        for (int j_ = 0; j_ < 4; j_++) \
            acc[i_][j_] = __builtin_amdgcn_mfma_f32_16x16x32_bf16(a[i_], b[j_], acc[i_][j_], 0, 0, 0); \
    __builtin_amdgcn_s_setprio(0); \
    _Pragma("unroll") \
    for (int i_ = 0; i_ < 4; i_++) \
        c[i_] = *(const bf16x8*)&sm2[CB][0][(wr128 + 64 + i_ * 16 + rl) * 32 + kg]; \
    if (DOSTG) SGB(NB, KN); \
    P_LGKM; \
    __builtin_amdgcn_s_setprio(1); \
    _Pragma("unroll") \
    for (int i_ = 0; i_ < 4; i_++) \
        _Pragma("unroll") \
        for (int j_ = 0; j_ < 4; j_++) \
            acc[4 + i_][j_] = __builtin_amdgcn_mfma_f32_16x16x32_bf16(c[i_], b[j_], acc[4 + i_][j_], 0, 0, 0); \
    __builtin_amdgcn_s_setprio(0); \
} while (0)

// OM: 0 = bf16 out (stride NN), 1 = f32 out (stride cs)
template <int OM>
__global__ __launch_bounds__(512, 2) void gemm256k(
    const u16* __restrict__ A, const u16* __restrict__ Bp,
    u16* __restrict__ Cb, float* __restrict__ Cf, int cs) {
    __shared__ u16 sm2[4][2][8192];

    const int brow = blockIdx.y * 256;
    const int bcol = blockIdx.x * 256;

    const int tid  = threadIdx.x;
    const int lane = tid & 63;
    const int wid  = tid >> 6;
    const int wr128 = (wid >> 2) * 128;
    const int wc64  = (wid & 3) * 64;
    const int rl = lane & 15;
    const int kq = lane >> 4;
    const int kg = (kq ^ ((rl >> 1) & 3)) * 8;

    const int r0 = tid >> 2;
    const int lb = (tid & 3) ^ ((r0 >> 1) & 3);
    const size_t aoff0 = (size_t)(brow + r0) * NN + lb * 8;
    const size_t aoff1 = aoff0 + (size_t)128 * NN;
    const size_t boff0 = (size_t)(bcol + r0) * NN + lb * 8;
    const size_t boff1 = boff0 + (size_t)128 * NN;

    f32x4 acc[8][4] = {};

    SGA(0, 0); SGB(0, 0); SGA(1, 32); SGB(1, 32);

    for (int tb = 0; tb < 31; ++tb) {
        const size_t k0 = (size_t)tb * 128;
        K256(0, 2, k0 + 64,  1, 4);
        K256(1, 3, k0 + 96,  1, 4);
        K256(2, 0, k0 + 128, 1, 4);
        K256(3, 1, k0 + 160, 1, 4);
    }
    K256(0, 2, 4032, 1, 4);
    K256(1, 3, 4064, 1, 4);
    K256(2, 0, 0,    0, 4);
    K256(3, 0, 0,    0, 0);

    const int rg = kq * 4;
#pragma unroll
    for (int fr = 0; fr < 8; fr++)
#pragma unroll
        for (int fc = 0; fc < 4; fc++) {
            const int col = bcol + wc64 + fc * 16 + rl;
#pragma unroll
            for (int e = 0; e < 4; e++) {
                const int row = brow + wr128 + fr * 16 + rg + e;
                if (OM == 0)
                    Cb[(size_t)row * NN + col] = f2bf(acc[fr][fc][e]);
                else
                    Cf[(size_t)row * cs + col] = acc[fr][fc][e];
            }
        }
}

extern "C" void kernel_launch(void* const* d_in, const int* in_sizes, int n_in,
                              void* d_out, int out_size, void* d_ws, size_t ws_size,
                              hipStream_t stream) {
    const float* x  = (const float*)d_in[0];
    const float* Wr = (const float*)d_in[1];
    const float* Wi = (const float*)d_in[2];
    float* out = (float*)d_out;

    const size_t SZ = (size_t)NN * NN;
    u16* ws = (u16*)d_ws;
    u16* s0 = ws;            // xb   -> WrT
    u16* s1 = ws + SZ;       // Wrb  -> WiT
    u16* s2 = ws + 2 * SZ;   // Wib  -> S_A ; later (s2,s3) = M2 f32
    u16* s3 = ws + 3 * SZ;   // Rtr
    u16* s4 = ws + 4 * SZ;   // Rti
    u16* s5 = ws + 5 * SZ;   // S_B
    float* M2 = (float*)s2;  // 64 MB f32 over s2+s3 (both dead by M2 launch)

    // 1) convert inputs to bf16
    cvt_bf16<<<8192, 256, 0, stream>>>(x,  s0);
    cvt_bf16<<<8192, 256, 0, stream>>>(Wr, s1);
    cvt_bf16<<<8192, 256, 0, stream>>>(Wi, s2);

    // 2) pass 1 on gemm256k (bf16 out): Rtr = NT(Wr, x), Rti = NT(Wi, x)
    gemm256k<0><<<dim3(16, 16), 512, 0, stream>>>(s1, s0, s3, nullptr, 0);
    gemm256k<0><<<dim3(16, 16), 512, 0, stream>>>(s2, s0, s4, nullptr, 0);

    // 3) weight prep: WrT -> s0, WiT -> s1, S_A -> s2 ; S_B = Rtr+Rti -> s5
    wprep<<<dim3(128, 128), dim3(32, 8), 0, stream>>>(Wr, Wi, s0, s1, s2);
    presum<<<8192, 256, 0, stream>>>(s3, s4, s5);

    // 4) pass 2 via Karatsuba (order: M3, M1, then M2 into dead s2/s3)
    gemm256k<1><<<dim3(16, 16), 512, 0, stream>>>(s2, s5, nullptr, out + NN, 2 * NN); // M3
    gemm256k<1><<<dim3(16, 16), 512, 0, stream>>>(s0, s3, nullptr, out,      2 * NN); // M1
    gemm256k<1><<<dim3(16, 16), 512, 0, stream>>>(s1, s4, nullptr, M2,       NN);     // M2

    // 5) combine (streaming, full occupancy): Cr = M1-M2, Ci = M3-M1-M2
    combine<<<16384, 256, 0, stream>>>(out, M2);
}